// Round 1
// baseline (125.952 us; speedup 1.0000x reference)
//
#include <hip/hip_runtime.h>
#include <hip/hip_bf16.h>

typedef __attribute__((ext_vector_type(8))) short short8;   // bf16x8 MFMA frag
typedef __attribute__((ext_vector_type(4))) float f32x4;

constexpr int N1 = 16384, N2 = 8192, N3 = 4096;
constexpr int WN = 36864;
constexpr float ISQ3 = 0.57735026918962576451f;

__device__ __forceinline__ unsigned short f2bf(float f) {
  unsigned u = __builtin_bit_cast(unsigned, f);
  u += 0x7fffu + ((u >> 16) & 1u);   // RNE
  return (unsigned short)(u >> 16);
}

// K0: H = relu(relu(weight@W0+b0)@W1+b1), f32 [4096][64]
__global__ void k_mlp(const float* __restrict__ wgt, const float* __restrict__ W0,
                      const float* __restrict__ b0, const float* __restrict__ W1,
                      const float* __restrict__ b1, float* __restrict__ H) {
  __shared__ float h0s[4][64];
  const int r = threadIdx.x >> 6, j = threadIdx.x & 63;
  const int e = blockIdx.x * 4 + r;
  float a = b0[j];
#pragma unroll
  for (int i = 0; i < 16; ++i) a = fmaf(wgt[e * 16 + i], W0[i * 64 + j], a);
  h0s[r][j] = fmaxf(a, 0.f);
  __syncthreads();
  float a1 = b1[j];
#pragma unroll
  for (int i = 0; i < 64; ++i) a1 = fmaf(h0s[r][i], W1[i * 64 + j], a1);
  H[e * 64 + j] = fmaxf(a1, 0.f);
}

// K1: W2 f32 [64][36864] -> Bp bf16 in exact B-frag layout.
// Bp flat idx = ((nt*2+kh)*64 + lane)*8 + j  holds  W2[kh*32 + (lane>>4)*8 + j][nt*16 + (lane&15)]
__global__ void k_permute(const float* __restrict__ W2, unsigned short* __restrict__ Bp) {
  const int g = blockIdx.x * 256 + threadIdx.x;
  const int lane = g & 63;
  const int nth = g >> 6;
  const int kh = nth & 1, nt = nth >> 1;
  const int n = nt * 16 + (lane & 15);
  const int k0 = kh * 32 + (lane >> 4) * 8;
  short8 v;
#pragma unroll
  for (int j = 0; j < 8; ++j) v[j] = (short)f2bf(W2[(size_t)(k0 + j) * WN + n]);
  *(short8*)(Bp + (size_t)g * 8) = v;
}

// K2: initialize d_out with the b2-contraction part + bias (fully overwrites d_out)
__global__ void k_init_out(const float* __restrict__ d1, const float* __restrict__ d2,
                           const float* __restrict__ b2, const float* __restrict__ bias,
                           float* __restrict__ out) {
  __shared__ float s1s[8][128];
  __shared__ float v1s[8][64][3];
  __shared__ float dts[8][64];
  __shared__ float s2s[8];
  __shared__ float v2s[8][3];
  const int e0 = blockIdx.x * 8;
  for (int x = threadIdx.x; x < 8 * 320; x += 256) {
    int e = x / 320, c = x % 320;
    float v = d1[(size_t)(e0 + e) * 320 + c];
    if (c < 128) s1s[e][c] = v;
    else { int q = c - 128; v1s[e][q / 3][q % 3] = v; }
  }
  if (threadIdx.x < 32) {
    int e = threadIdx.x >> 2, c = threadIdx.x & 3;
    float v = d2[(size_t)(e0 + e) * 4 + c];
    if (c == 0) s2s[e] = v; else v2s[e][c - 1] = v;
  }
  __syncthreads();
  for (int x = threadIdx.x; x < 8 * 64; x += 256) {
    int e = x >> 6, u = x & 63;
    dts[e][u] = v1s[e][u][0] * v2s[e][0] + v1s[e][u][1] * v2s[e][1] + v1s[e][u][2] * v2s[e][2];
  }
  __syncthreads();
  for (int c = threadIdx.x; c < 320; c += 256) {
    if (c < 128) {
      const int w = c;
      float ta[8] = {0,0,0,0,0,0,0,0}, td[8] = {0,0,0,0,0,0,0,0};
      for (int u = 0; u < 128; ++u) {
        float bv = b2[u * 128 + w];
#pragma unroll
        for (int e = 0; e < 8; ++e) ta[e] = fmaf(s1s[e][u], bv, ta[e]);
      }
      for (int u = 0; u < 64; ++u) {
        float bv = b2[N1 + N2 + N3 + u * 128 + w];
#pragma unroll
        for (int e = 0; e < 8; ++e) td[e] = fmaf(dts[e][u], bv, td[e]);
      }
      const float bw = bias[w];
#pragma unroll
      for (int e = 0; e < 8; ++e)
        out[(size_t)(e0 + e) * 320 + c] = fmaf(s2s[e], ta[e], ISQ3 * td[e]) + bw;
    } else {
      const int q = c - 128, w = q / 3, i = q % 3;
      float tb[8] = {0,0,0,0,0,0,0,0}, tc[8] = {0,0,0,0,0,0,0,0};
      for (int u = 0; u < 128; ++u) {
        float bv = b2[N1 + u * 64 + w];
#pragma unroll
        for (int e = 0; e < 8; ++e) tb[e] = fmaf(s1s[e][u], bv, tb[e]);
      }
      for (int u = 0; u < 64; ++u) {
        float bv = b2[N1 + N2 + u * 64 + w];
#pragma unroll
        for (int e = 0; e < 8; ++e) tc[e] = fmaf(v1s[e][u][i], bv, tc[e]);
      }
#pragma unroll
      for (int e = 0; e < 8; ++e)
        out[(size_t)(e0 + e) * 320 + c] = tb[e] * v2s[e][i] + tc[e] * s2s[e];
    }
  }
}

// K3: fused GEMM (H @ W2, MFMA bf16) + u-reduction, atomicAdd partials into out.
// grid = 128 e-tiles (32 rows) x 4 u-quarters; 4 waves/WG.
__global__ __launch_bounds__(256, 2)
void k_main(const float* __restrict__ d1, const float* __restrict__ d2,
            const float* __restrict__ H, const unsigned short* __restrict__ Bp,
            float* __restrict__ out) {
  const int et = blockIdx.x >> 2;
  const int uq = blockIdx.x & 3;
  const int e0 = et * 32;
  const int tid = threadIdx.x;
  const int wid = tid >> 6, lane = tid & 63;
  const int nl = lane & 15, grp = lane >> 4;

  __shared__ __align__(16) float s1T[32][36];     // [u_local][e_local], a/b: u = uq*32+ul
  __shared__ __align__(16) float v1T[16][3][36];  // c: u = uq*16+ul
  __shared__ __align__(16) float dtT[16][36];     // d
  __shared__ float s2s[32];
  __shared__ float v2s[32][3];

  for (int x = tid; x < 32 * 32; x += 256) {
    int e = x >> 5, ul = x & 31;
    s1T[ul][e] = d1[(size_t)(e0 + e) * 320 + uq * 32 + ul];
  }
  for (int x = tid; x < 32 * 48; x += 256) {
    int e = x / 48, q = x % 48;
    v1T[q / 3][q % 3][e] = d1[(size_t)(e0 + e) * 320 + 128 + uq * 48 + q];
  }
  if (tid < 128) {
    int e = tid >> 2, c = tid & 3;
    float v = d2[(size_t)(e0 + e) * 4 + c];
    if (c == 0) s2s[e] = v; else v2s[e][c - 1] = v;
  }
  __syncthreads();
  for (int x = tid; x < 16 * 32; x += 256) {
    int ul = x >> 5, e = x & 31;
    dtT[ul][e] = v1T[ul][0][e] * v2s[e][0] + v1T[ul][1][e] * v2s[e][1] + v1T[ul][2][e] * v2s[e][2];
  }

  // A-frags: H rows e0 + m*16 + (lane&15), k = kh*32 + grp*8 + j  (register-resident)
  short8 hA[2][2];
#pragma unroll
  for (int m = 0; m < 2; ++m)
#pragma unroll
    for (int kh = 0; kh < 2; ++kh) {
      const float* hp = H + (size_t)(e0 + m * 16 + nl) * 64 + kh * 32 + grp * 8;
      short8 v;
#pragma unroll
      for (int j = 0; j < 8; ++j) v[j] = (short)f2bf(hp[j]);
      hA[m][kh] = v;
    }
  __syncthreads();

  f32x4 accA[2][2] = {};
  f32x4 accB[2] = {};
  f32x4 accC[2][3] = {};
  f32x4 accD[2][2] = {};

  // ---- blocks a (nt = ua*8 + wt) and b (nt = 1024 + ub*4 + wid), u range uq*32..+31 ----
#pragma unroll 2
  for (int ul = 0; ul < 32; ++ul) {
    const int uu = uq * 32 + ul;
    f32x4 s1v[2];
#pragma unroll
    for (int m = 0; m < 2; ++m) s1v[m] = *(const f32x4*)&s1T[ul][m * 16 + grp * 4];
#pragma unroll
    for (int wl = 0; wl < 2; ++wl) {
      const int nt = uu * 8 + 2 * wid + wl;
      const short8* bp = (const short8*)(Bp + (size_t)nt * 1024 + lane * 8);
      short8 bf0 = bp[0], bf1 = bp[64];
#pragma unroll
      for (int m = 0; m < 2; ++m) {
        f32x4 t = {0.f, 0.f, 0.f, 0.f};
        t = __builtin_amdgcn_mfma_f32_16x16x32_bf16(hA[m][0], bf0, t, 0, 0, 0);
        t = __builtin_amdgcn_mfma_f32_16x16x32_bf16(hA[m][1], bf1, t, 0, 0, 0);
        accA[m][wl] += s1v[m] * t;
      }
    }
    {
      const int nt = 1024 + uu * 4 + wid;
      const short8* bp = (const short8*)(Bp + (size_t)nt * 1024 + lane * 8);
      short8 bf0 = bp[0], bf1 = bp[64];
#pragma unroll
      for (int m = 0; m < 2; ++m) {
        f32x4 t = {0.f, 0.f, 0.f, 0.f};
        t = __builtin_amdgcn_mfma_f32_16x16x32_bf16(hA[m][0], bf0, t, 0, 0, 0);
        t = __builtin_amdgcn_mfma_f32_16x16x32_bf16(hA[m][1], bf1, t, 0, 0, 0);
        accB[m] += s1v[m] * t;
      }
    }
  }

  // ---- blocks d (nt = 1792 + ud*8 + wt) and c (nt = 1536 + uc*4 + wid), u range uq*16..+15 ----
#pragma unroll 2
  for (int ul = 0; ul < 16; ++ul) {
    const int uu = uq * 16 + ul;
    f32x4 dv[2];
#pragma unroll
    for (int m = 0; m < 2; ++m) dv[m] = *(const f32x4*)&dtT[ul][m * 16 + grp * 4];
#pragma unroll
    for (int wl = 0; wl < 2; ++wl) {
      const int nt = 1792 + uu * 8 + 2 * wid + wl;
      const short8* bp = (const short8*)(Bp + (size_t)nt * 1024 + lane * 8);
      short8 bf0 = bp[0], bf1 = bp[64];
#pragma unroll
      for (int m = 0; m < 2; ++m) {
        f32x4 t = {0.f, 0.f, 0.f, 0.f};
        t = __builtin_amdgcn_mfma_f32_16x16x32_bf16(hA[m][0], bf0, t, 0, 0, 0);
        t = __builtin_amdgcn_mfma_f32_16x16x32_bf16(hA[m][1], bf1, t, 0, 0, 0);
        accD[m][wl] += dv[m] * t;
      }
    }
    {
      const int nt = 1536 + uu * 4 + wid;
      const short8* bp = (const short8*)(Bp + (size_t)nt * 1024 + lane * 8);
      short8 bf0 = bp[0], bf1 = bp[64];
#pragma unroll
      for (int m = 0; m < 2; ++m) {
        f32x4 t = {0.f, 0.f, 0.f, 0.f};
        t = __builtin_amdgcn_mfma_f32_16x16x32_bf16(hA[m][0], bf0, t, 0, 0, 0);
        t = __builtin_amdgcn_mfma_f32_16x16x32_bf16(hA[m][1], bf1, t, 0, 0, 0);
#pragma unroll
        for (int i = 0; i < 3; ++i) {
          f32x4 vv = *(const f32x4*)&v1T[ul][i][m * 16 + grp * 4];
          accC[m][i] += vv * t;
        }
      }
    }
  }

  // ---- epilogue: out0 = s2*ta + td/sqrt3 (+bias in K2); out1[w,i] = tb*v2_i + tc_i*s2 ----
#pragma unroll
  for (int m = 0; m < 2; ++m) {
#pragma unroll
    for (int r = 0; r < 4; ++r) {
      const int el = m * 16 + grp * 4 + r;
      const float s2v = s2s[el];
      float* orow = out + (size_t)(e0 + el) * 320;
#pragma unroll
      for (int wl = 0; wl < 2; ++wl) {
        const int w = (2 * wid + wl) * 16 + nl;
        atomicAdd(orow + w, s2v * accA[m][wl][r] + ISQ3 * accD[m][wl][r]);
      }
      const int w = wid * 16 + nl;
#pragma unroll
      for (int i = 0; i < 3; ++i)
        atomicAdd(orow + 128 + 3 * w + i, accB[m][r] * v2s[el][i] + accC[m][i][r] * s2v);
    }
  }
}

extern "C" void kernel_launch(void* const* d_in, const int* in_sizes, int n_in,
                              void* d_out, int out_size, void* d_ws, size_t ws_size,
                              hipStream_t stream) {
  const float* d1   = (const float*)d_in[0];
  const float* d2   = (const float*)d_in[1];
  const float* wgt  = (const float*)d_in[2];
  const float* W0   = (const float*)d_in[3];
  const float* b0   = (const float*)d_in[4];
  const float* W1   = (const float*)d_in[5];
  const float* b1   = (const float*)d_in[6];
  const float* W2   = (const float*)d_in[7];
  const float* b2   = (const float*)d_in[8];
  const float* bias = (const float*)d_in[9];
  float* out = (float*)d_out;

  float* H = (float*)d_ws;                                      // 4096*64*4 = 1 MiB
  unsigned short* Bp = (unsigned short*)((char*)d_ws + (size_t)4096 * 64 * 4);  // 4.72 MB bf16

  k_mlp<<<1024, 256, 0, stream>>>(wgt, W0, b0, W1, b1, H);
  k_permute<<<1152, 256, 0, stream>>>(W2, Bp);
  k_init_out<<<512, 256, 0, stream>>>(d1, d2, b2, bias, out);
  k_main<<<512, 256, 0, stream>>>(d1, d2, H, Bp, out);
}